// Round 15
// baseline (745.828 us; speedup 1.0000x reference)
//
#include <hip/hip_runtime.h>

typedef unsigned short us;
typedef __bf16 v8bf __attribute__((ext_vector_type(8)));
typedef float v16f __attribute__((ext_vector_type(16)));
typedef float v4f __attribute__((ext_vector_type(4)));
typedef us us4v __attribute__((ext_vector_type(4)));
typedef us us8v __attribute__((ext_vector_type(8)));
typedef float f4v __attribute__((ext_vector_type(4)));

#define SCALE 0.08838834764831845f

__device__ __forceinline__ us f2bf(float f) {
  unsigned u = __builtin_bit_cast(unsigned, f);
  u += 0x7fffu + ((u >> 16) & 1u);
  return (us)(u >> 16);
}
__device__ __forceinline__ float bf2f(us h) {
  unsigned u = ((unsigned)h) << 16;
  return __builtin_bit_cast(float, u);
}

typedef const __attribute__((address_space(1))) void* gas_t;
typedef __attribute__((address_space(3))) void* las_t;
#define GLD16(gp, lp) __builtin_amdgcn_global_load_lds((gas_t)(gp), (las_t)(lp), 16, 0, 0)

// ---------------- fp32 -> bf16 casts (R12 sequencing: wo cast must run AFTER
// the QKV GEMM because woB aliases the middle of wqB) ----------------
__global__ void cast_kernel(const float* __restrict__ in, us* __restrict__ out, int n) {
  int stride = gridDim.x * blockDim.x * 4;
  for (int i = (blockIdx.x * blockDim.x + threadIdx.x) * 4; i < n; i += stride) {
    f4v f = *(const f4v*)(in + i);
    us4v o;
#pragma unroll
    for (int j = 0; j < 4; ++j) o[j] = f2bf(f[j]);
    *(us4v*)(out + i) = o;
  }
}

__global__ void cast2_kernel(const float* __restrict__ a, us* __restrict__ oa, int na,
                             const float* __restrict__ b, us* __restrict__ ob, int nb) {
  int total = na + nb;
  int stride = gridDim.x * blockDim.x * 4;
  for (int i = (blockIdx.x * blockDim.x + threadIdx.x) * 4; i < total; i += stride) {
    const float* s = (i < na) ? (a + i) : (b + (i - na));
    us* d = (i < na) ? (oa + i) : (ob + (i - na));
    f4v f = *(const f4v*)s;
    us4v o;
#pragma unroll
    for (int j = 0; j < 4; ++j) o[j] = f2bf(f[j]);
    *(us4v*)d = o;
  }
}

// ---------------- 256x256 GEMM, R15: R12 schedule + 32x32x16 MFMA ------------
// R12's sync skeleton EXACTLY (stage slots A(t+1)@ph0/ph1, B(t+2)@ph2/ph3+VMC4,
// A(t+2)@ph4/ph5, B(t+3)@ph6/ph7+VMC4; post-barrier q00 reads — race-free per
// R12 proof). MFMA 32x32x16: 21% more FLOP/cyc (2382 vs 2075 TF ubench), half
// the MFMA instructions, identical LDS volume. R13's identical-absmax evidence
// shows this port computes the same function as the 16x16 version — R13/R14's
// failure was cast3's woB/wqB aliasing, NOT this layout.
// A/B frag: lane l holds row/col = l&31, k = (l>>5)*8 + 0..7 per 16-k slice.
// C/D: col=lane&31, row=(r&3)+8*(r>>2)+4*(lane>>5) [m74/m101]. Wave owns
// n-blocks {bb, bb+64} of ONE head => RoPE partner = acc[m][n^1][r].
template <int EPI>
__global__ __launch_bounds__(512, 2) void gemm8(
    const us* __restrict__ A, const us* __restrict__ Bt, int M, int N, int K,
    float* __restrict__ outF, us* __restrict__ outQ, us* __restrict__ outK,
    us* __restrict__ outV, const float* __restrict__ cosT,
    const float* __restrict__ sinT, int MT) {
  __shared__ us lds[65536];  // buf0: A[0,16384) B[16384,32768); buf1: +32768
  const int tid = threadIdx.x, lane = tid & 63, w = tid >> 6;
  const int nwg = gridDim.x;
  const int bid = blockIdx.x;
  const int cpx = nwg >> 3;
  const int swz = (bid & 7) * cpx + (bid >> 3);  // grids %8==0 (768, 256)
  const int bm = swz % MT, bn = swz / MT;
  const int row0 = bm * 256, col0 = bn * 256;
  const int wr = w >> 2, wc = w & 3;
  const int lr5 = lane & 31, hk = lane >> 5;
  const int NTK = K >> 6;  // even, >=4 (64)

#define STAGE_A(t, p, j)                                                      \
  do {                                                                        \
    int q_ = (j) * 512 + tid;                                                 \
    int row_ = q_ >> 3, cph_ = q_ & 7;                                        \
    GLD16(A + (long)(row0 + row_) * K + (t) * 64 + ((cph_ ^ (row_ & 7)) * 8), \
          &lds[(p) * 32768 + ((j) * 512 + w * 64) * 8]);                      \
  } while (0)
#define STAGE_B(t, p, j)                                                      \
  do {                                                                        \
    int q_ = (j) * 512 + tid;                                                 \
    int row_ = q_ >> 3, cph_ = q_ & 7;                                        \
    GLD16(Bt + (long)(col0 + row_) * K + (t) * 64 + ((cph_ ^ (row_ & 7)) * 8),\
          &lds[(p) * 32768 + 16384 + ((j) * 512 + w * 64) * 8]);              \
  } while (0)

  // swizzled fragment load: ks in [0,4) selects a 16-k slice; lane covers
  // k = ks*16 + hk*8 + 0..7 -> global chunk ks*2+hk, physical = ^ (row&7)
#define LDF2(base, row, ks) \
  (*(const v8bf*)&(base)[(row) * 64 + ((((ks) * 2 + hk) ^ ((row) & 7)) * 8)])

#define RD_A(base, mofs, ksofs)                                               \
  _Pragma("unroll") for (int mm = 0; mm < 2; ++mm)                            \
  _Pragma("unroll") for (int kk = 0; kk < 2; ++kk)                            \
    af[mm][kk] = LDF2(base, ar0 + ((mofs) + mm) * 32, (ksofs) + kk);
#define RD_B(dst, base, ksofs)                                                \
  _Pragma("unroll") for (int nn = 0; nn < 2; ++nn)                            \
  _Pragma("unroll") for (int kk = 0; kk < 2; ++kk)                            \
    dst[nn][kk] = LDF2(base, bb + nn * 64 + lr5, (ksofs) + kk);

#define HM32(mb, Bf)                                                          \
  _Pragma("unroll") for (int kk = 0; kk < 2; ++kk)                            \
  _Pragma("unroll") for (int mm = 0; mm < 2; ++mm)                            \
  _Pragma("unroll") for (int nn = 0; nn < 2; ++nn)                            \
    acc[(mb) + mm][nn] = __builtin_amdgcn_mfma_f32_32x32x16_bf16(             \
        af[mm][kk], Bf[nn][kk], acc[(mb) + mm][nn], 0, 0, 0);

#define BARR __builtin_amdgcn_s_barrier()
#define LGKM0 asm volatile("s_waitcnt lgkmcnt(0)" ::: "memory")
#define PRIO1 __builtin_amdgcn_s_setprio(1)
#define PRIO0 __builtin_amdgcn_s_setprio(0)
#define VMC4 asm volatile("s_waitcnt vmcnt(4)" ::: "memory")
#define VMC0 asm volatile("s_waitcnt vmcnt(0)" ::: "memory")

  v16f acc[4][2];
#pragma unroll
  for (int m = 0; m < 4; ++m)
#pragma unroll
    for (int n = 0; n < 2; ++n)
#pragma unroll
      for (int j = 0; j < 16; ++j) acc[m][n][j] = 0.f;

  const us* B0a = &lds[0];
  const us* B0b = &lds[16384];
  const us* B1a = &lds[32768];
  const us* B1b = &lds[49152];
  const int ar0 = wr * 128 + lr5;
  const int bb = (wc >> 1) * 128 + (wc & 1) * 32;  // wave col base (blocks bb, bb+64)

  // prologue (R12): A(0),B(0) -> buf0; B(1) -> buf1. VMC4 drains tile0 for
  // every wave (leaves B(1)'s 4). BARR => buf0 globally valid.
  STAGE_A(0, 0, 0); STAGE_A(0, 0, 1); STAGE_A(0, 0, 2); STAGE_A(0, 0, 3);
  STAGE_B(0, 0, 0); STAGE_B(0, 0, 1); STAGE_B(0, 0, 2); STAGE_B(0, 0, 3);
  STAGE_B(1, 1, 0); STAGE_B(1, 1, 1); STAGE_B(1, 1, 2); STAGE_B(1, 1, 3);
  VMC4;
  BARR;

  v8bf af[2][2], bf_lo[2][2], bf_hi[2][2];

  for (int t = 0; t < NTK; t += 2) {
    // ======== tile t (buf0) ========
    // ph0: q00 reads (A[m01][ks01]+B[ks01], post-barrier SAFE) | MFMA q00 |
    //      post-reads A[m01][ks23]+B[ks23] | stage A(t+1) j0,j1
    RD_A(B0a, 0, 0); RD_B(bf_lo, B0b, 0);
    LGKM0; PRIO1; HM32(0, bf_lo); PRIO0;
    RD_A(B0a, 0, 2); RD_B(bf_hi, B0b, 2);
    STAGE_A(t + 1, 1, 0); STAGE_A(t + 1, 1, 1);
    BARR;
    // ph1: MFMA q01 (m01 x ks23) | read A[m23][ks01] | stage A(t+1) j2,j3
    LGKM0; PRIO1; HM32(0, bf_hi); PRIO0;
    RD_A(B0a, 2, 0);
    STAGE_A(t + 1, 1, 2); STAGE_A(t + 1, 1, 3);
    BARR;
    // ph2: MFMA q10 (m23 x ks01) | read A[m23][ks23] | stage B(t+2) j0,j1
    LGKM0; PRIO1; HM32(2, bf_lo); PRIO0;
    RD_A(B0a, 2, 2);
    if (t + 2 < NTK) { STAGE_B(t + 2, 0, 0); STAGE_B(t + 2, 0, 1); }
    BARR;
    // ph3: MFMA q11 | stage B(t+2) j2,j3 | VMC4: leaves only B(t+2)j0-3 =>
    //      A(t+1)+B(t+1) drained by EVERY wave => ph3-end BARR = buf1 valid
    LGKM0; PRIO1; HM32(2, bf_hi); PRIO0;
    if (t + 2 < NTK) { STAGE_B(t + 2, 0, 2); STAGE_B(t + 2, 0, 3); VMC4; }
    else { VMC0; }
    BARR;
    // ======== tile t+1 (buf1) ========
    // ph4: q00 reads of buf1 (SAFE) | MFMA q00 | post-reads | stage A(t+2) j0,j1
    RD_A(B1a, 0, 0); RD_B(bf_lo, B1b, 0);
    LGKM0; PRIO1; HM32(0, bf_lo); PRIO0;
    RD_A(B1a, 0, 2); RD_B(bf_hi, B1b, 2);
    if (t + 2 < NTK) { STAGE_A(t + 2, 0, 0); STAGE_A(t + 2, 0, 1); }
    BARR;
    // ph5: MFMA q01 | read A[m23][ks01] | stage A(t+2) j2,j3
    LGKM0; PRIO1; HM32(0, bf_hi); PRIO0;
    RD_A(B1a, 2, 0);
    if (t + 2 < NTK) { STAGE_A(t + 2, 0, 2); STAGE_A(t + 2, 0, 3); }
    BARR;
    // ph6: MFMA q10 | read A[m23][ks23] | stage B(t+3) j0,j1
    LGKM0; PRIO1; HM32(2, bf_lo); PRIO0;
    RD_A(B1a, 2, 2);
    if (t + 3 < NTK) { STAGE_B(t + 3, 1, 0); STAGE_B(t + 3, 1, 1); }
    BARR;
    // ph7: MFMA q11 | stage B(t+3) j2,j3 | VMC4 => ph7-end BARR = buf0 valid
    LGKM0; PRIO1; HM32(2, bf_hi); PRIO0;
    if (t + 3 < NTK) { STAGE_B(t + 3, 1, 2); STAGE_B(t + 3, 1, 3); VMC4; }
    else if (t + 2 < NTK) { VMC0; }
    BARR;
  }
#undef STAGE_A
#undef STAGE_B

  // C/D layout (32x32): col = lane&31, row = (r&3) + 8*(r>>2) + 4*hk
  if (EPI == 0) {
#pragma unroll
    for (int m = 0; m < 4; ++m) {
#pragma unroll
      for (int r = 0; r < 16; ++r) {
        int row = row0 + wr * 128 + m * 32 + (r & 3) + 8 * (r >> 2) + 4 * hk;
#pragma unroll
        for (int n = 0; n < 2; ++n) {
          int col = col0 + bb + n * 64 + lr5;
          outF[(long)row * N + col] = acc[m][n][r];
        }
      }
    }
  } else {
    // fused RoPE epilogue, register-local (partner = n^1: cols bb vs bb+64)
    const int cbase = col0 + (wc >> 1) * 128;  // head-block base column
    const int which = cbase >> 12;             // 0=Q 1=K 2=V
    const int h = (cbase >> 7) & 31;
    const int dl = (wc & 1) * 32 + lr5;        // d & 63
    us* base = (which == 0) ? outQ : ((which == 1) ? outK : outV);
#pragma unroll
    for (int m = 0; m < 4; ++m) {
#pragma unroll
      for (int r = 0; r < 16; ++r) {
        int trow = row0 + wr * 128 + m * 32 + (r & 3) + 8 * (r >> 2) + 4 * hk;
        int b2 = trow >> 10, spos = trow & 1023;
        us* rowp = base + ((b2 * 32 + h) * 1024 + spos) * 128;
        if (which < 2) {
          float c = cosT[(long)trow * 64 + dl];
          float s = sinT[(long)trow * 64 + dl];
          float x1 = acc[m][0][r], x2 = acc[m][1][r];
          rowp[dl] = f2bf(x1 * c - x2 * s);
          rowp[64 + dl] = f2bf(x2 * c + x1 * s);
        } else {
          rowp[dl] = f2bf(acc[m][0][r]);
          rowp[64 + dl] = f2bf(acc[m][1][r]);
        }
      }
    }
  }
}

// ---------------- V transpose: [bh][s][d] -> [bh][d][s] ----------------
__global__ void transpose_v(const us* __restrict__ V, us* __restrict__ Vt) {
  __shared__ us tile[64][66];
  const int tid = threadIdx.x;
  const int s0 = blockIdx.x * 64;
  const int d0 = blockIdx.y * 64;
  const int bh = blockIdx.z;
  const us* Vb = V + (long)bh * 131072;
  us* Vtb = Vt + (long)bh * 131072;
  const int rr = tid >> 2, cq = tid & 3;
  us8v v0 = *(const us8v*)(Vb + (s0 + rr) * 128 + d0 + cq * 16);
  us8v v1 = *(const us8v*)(Vb + (s0 + rr) * 128 + d0 + cq * 16 + 8);
#pragma unroll
  for (int j = 0; j < 8; ++j) {
    tile[rr][cq * 16 + j] = v0[j];
    tile[rr][cq * 16 + 8 + j] = v1[j];
  }
  __syncthreads();
  us8v o0, o1;
#pragma unroll
  for (int j = 0; j < 8; ++j) {
    o0[j] = tile[cq * 16 + j][rr];
    o1[j] = tile[cq * 16 + 8 + j][rr];
  }
  *(us8v*)(Vtb + (d0 + rr) * 1024 + s0 + cq * 16) = o0;
  *(us8v*)(Vtb + (d0 + rr) * 1024 + s0 + cq * 16 + 8) = o1;
}

// ---------------- causal flash attention (R6 body + R14 XCD-coloring) --------
// Remap (xcd = L&7, W = L>>3) -> bh = xcd*16 + (W&15), qpair = W>>4
// (bijective; load balance preserved: every block runs the (qt, 7-qt) pair).
// Each XCD's co-resident blocks share 16 bh (8MB KV, ~2xL2) and the 4 blocks
// of one bh are co-located -> KV re-reads hit that XCD's L2.
__global__ __launch_bounds__(256, 2) void attn_kernel(
    const us* __restrict__ Q, const us* __restrict__ Kg,
    const us* __restrict__ Vt, us* __restrict__ Out) {
  __shared__ us Ks[2][8192];
  __shared__ us Vs[2][8192];
  __shared__ us Ps[4 * 2048];
  const int tid = threadIdx.x, lane = tid & 63, w = tid >> 6;
  const int L = (int)blockIdx.y * 4 + (int)blockIdx.x;  // dispatch-linear
  const int xcd = L & 7, W = L >> 3;
  const int bh = xcd * 16 + (W & 15);
  const int qpair = W >> 4;  // [0,4)
  const int lr = lane & 15, lg = lane >> 4;
  const us* Kbase = Kg + (long)bh * 131072;
  const us* Vbase = Vt + (long)bh * 131072;
  us* Pw = &Ps[w * 2048];
  const int b = bh >> 5, h = bh & 31;

#define STAGE_KV(kt, bf)                                                      \
  do {                                                                        \
    _Pragma("unroll") for (int i_ = 0; i_ < 4; ++i_) {                        \
      int c_ = (i_ * 4 + w) * 64 + lane;                                      \
      int rk_ = c_ >> 4, pc_ = c_ & 15;                                       \
      GLD16(Kbase + ((kt) * 64 + rk_) * 128 + ((pc_ ^ (rk_ & 7)) * 8),        \
            &Ks[bf][(i_ * 4 + w) * 512]);                                     \
    }                                                                         \
    _Pragma("unroll") for (int i_ = 0; i_ < 4; ++i_) {                        \
      int c_ = (i_ * 4 + w) * 64 + lane;                                      \
      int dd_ = c_ >> 3, pc_ = c_ & 7;                                        \
      GLD16(Vbase + dd_ * 1024 + (kt) * 64 + ((pc_ ^ (dd_ & 7)) * 8),         \
            &Vs[bf][(i_ * 4 + w) * 512]);                                     \
    }                                                                         \
  } while (0)

#pragma unroll 1
  for (int qsel = 0; qsel < 2; ++qsel) {
    const int qt = qsel ? qpair : 7 - qpair;
    const int q0 = qt * 128 + w * 32;

    v8bf qf[2][4];
    const us* Qb = Q + ((long)bh * 1024 + q0) * 128;
#pragma unroll
    for (int mq = 0; mq < 2; ++mq)
#pragma unroll
      for (int ks = 0; ks < 4; ++ks)
        qf[mq][ks] = *(const v8bf*)(Qb + (mq * 16 + lr) * 128 + ks * 32 + lg * 8);

    float m_run[2][4], l_run[2][4];
    v4f o_acc[2][8];
#pragma unroll
    for (int mq = 0; mq < 2; ++mq) {
#pragma unroll
      for (int r = 0; r < 4; ++r) {
        m_run[mq][r] = -1e30f;
        l_run[mq][r] = 0.f;
      }
#pragma unroll
      for (int nd = 0; nd < 8; ++nd)
#pragma unroll
        for (int j = 0; j < 4; ++j) o_acc[mq][nd][j] = 0.f;
    }

    const int nkt = 2 * qt + 2;
    STAGE_KV(0, 0);
    for (int kt = 0; kt < nkt; ++kt) {
      const int cb = kt & 1;
      if (kt + 1 < nkt) {
        STAGE_KV(kt + 1, cb ^ 1);
        asm volatile("s_waitcnt vmcnt(8)" ::: "memory");
      } else {
        asm volatile("s_waitcnt vmcnt(0)" ::: "memory");
      }
      __builtin_amdgcn_s_barrier();

      v4f sacc[2][4];
#pragma unroll
      for (int mq = 0; mq < 2; ++mq)
#pragma unroll
        for (int nk = 0; nk < 4; ++nk)
#pragma unroll
          for (int j = 0; j < 4; ++j) sacc[mq][nk][j] = 0.f;
      __builtin_amdgcn_s_setprio(1);
#pragma unroll
      for (int nk = 0; nk < 4; ++nk) {
        int key = nk * 16 + lr;
#pragma unroll
        for (int ks = 0; ks < 4; ++ks) {
          int pc = (ks * 4 + lg) ^ (key & 7);
          v8bf kf = *(const v8bf*)(&Ks[cb][key * 128 + pc * 8]);
          sacc[0][nk] = __builtin_amdgcn_mfma_f32_16x16x32_bf16(qf[0][ks], kf, sacc[0][nk], 0, 0, 0);
          sacc[1][nk] = __builtin_amdgcn_mfma_f32_16x16x32_bf16(qf[1][ks], kf, sacc[1][nk], 0, 0, 0);
        }
      }
      __builtin_amdgcn_s_setprio(0);

      const bool needMask = (kt * 64 + 63) > q0;
#pragma unroll
      for (int mq = 0; mq < 2; ++mq)
#pragma unroll
        for (int nk = 0; nk < 4; ++nk)
#pragma unroll
          for (int r = 0; r < 4; ++r) {
            float sv = sacc[mq][nk][r] * SCALE;
            if (needMask && (kt * 64 + nk * 16 + lr) > (q0 + mq * 16 + lg * 4 + r)) sv = -1e30f;
            sacc[mq][nk][r] = sv;
          }

      float pm[2][4];
      float need = 0.f;
#pragma unroll
      for (int mq = 0; mq < 2; ++mq)
#pragma unroll
        for (int r = 0; r < 4; ++r) {
          float p = fmaxf(fmaxf(sacc[mq][0][r], sacc[mq][1][r]),
                          fmaxf(sacc[mq][2][r], sacc[mq][3][r]));
          p = fmaxf(p, __shfl_xor(p, 1));
          p = fmaxf(p, __shfl_xor(p, 2));
          p = fmaxf(p, __shfl_xor(p, 4));
          p = fmaxf(p, __shfl_xor(p, 8));
          pm[mq][r] = p;
          need = fmaxf(need, p - m_run[mq][r]);
        }
      if (__any(need > 8.f)) {
#pragma unroll
        for (int mq = 0; mq < 2; ++mq)
#pragma unroll
          for (int r = 0; r < 4; ++r) {
            float mnew = fmaxf(m_run[mq][r], pm[mq][r]);
            float alpha = __expf(m_run[mq][r] - mnew);
            m_run[mq][r] = mnew;
            l_run[mq][r] *= alpha;
#pragma unroll
            for (int nd = 0; nd < 8; ++nd)
#pragma unroll
              for (int j = 0; j < 4; ++j) o_acc[mq][nd][j] = (j == r) ? o_acc[mq][nd][j] * alpha : o_acc[mq][nd][j];
          }
      }

      float rsum[2][4];
#pragma unroll
      for (int mq = 0; mq < 2; ++mq)
#pragma unroll
        for (int r = 0; r < 4; ++r) rsum[mq][r] = 0.f;
#pragma unroll
      for (int mq = 0; mq < 2; ++mq)
#pragma unroll
        for (int nk = 0; nk < 4; ++nk) {
          int key = nk * 16 + lr;
#pragma unroll
          for (int r = 0; r < 4; ++r) {
            float p = __expf(sacc[mq][nk][r] - m_run[mq][r]);
            rsum[mq][r] += p;
            int qrow = mq * 16 + lg * 4 + r;
            int pcw = (key >> 3) ^ (qrow & 7);
            Pw[qrow * 64 + pcw * 8 + (key & 7)] = f2bf(p);
          }
        }

#pragma unroll
      for (int mq = 0; mq < 2; ++mq)
#pragma unroll
        for (int r = 0; r < 4; ++r) {
          float rs = rsum[mq][r];
          rs += __shfl_xor(rs, 1);
          rs += __shfl_xor(rs, 2);
          rs += __shfl_xor(rs, 4);
          rs += __shfl_xor(rs, 8);
          l_run[mq][r] += rs;
        }

      __builtin_amdgcn_s_setprio(1);
#pragma unroll
      for (int kk = 0; kk < 2; ++kk) {
        v8bf pa[2];
#pragma unroll
        for (int mq = 0; mq < 2; ++mq) {
          int q = mq * 16 + lr;
          int pc = (kk * 4 + lg) ^ (q & 7);
          pa[mq] = *(const v8bf*)(&Pw[q * 64 + pc * 8]);
        }
#pragma unroll
        for (int nd = 0; nd < 8; ++nd) {
          int d = nd * 16 + lr;
          int pc = (kk * 4 + lg) ^ (d & 7);
          v8bf vb = *(const v8bf*)(&Vs[cb][d * 64 + pc * 8]);
          o_acc[0][nd] = __builtin_amdgcn_mfma_f32_16x16x32_bf16(pa[0], vb, o_acc[0][nd], 0, 0, 0);
          o_acc[1][nd] = __builtin_amdgcn_mfma_f32_16x16x32_bf16(pa[1], vb, o_acc[1][nd], 0, 0, 0);
        }
      }
      __builtin_amdgcn_s_setprio(0);
      __builtin_amdgcn_s_barrier();
    }

#pragma unroll
    for (int mq = 0; mq < 2; ++mq)
#pragma unroll
      for (int r = 0; r < 4; ++r) {
        int srow = q0 + mq * 16 + lg * 4 + r;
        float inv = 1.f / l_run[mq][r];
        us* orow = Out + ((long)b * 1024 + srow) * 4096 + h * 128;
#pragma unroll
        for (int nd = 0; nd < 8; ++nd) orow[nd * 16 + lr] = f2bf(o_acc[mq][nd][r] * inv);
      }
  }
#undef STAGE_KV
}

// ---------------- launcher ----------------
// ws layout (bytes), peak 224 MB with reuse. LIFETIME NOTE: woB (64M..96M)
// aliases the middle of wqB (32M..128M) — the wo cast MUST run after the QKV
// GEMM (R13/R14 fused it into the first cast and corrupted the V weights).
//  [0,   32M)  hidden_bf16  -> reused as Vt after QKV GEMM
//  [32M, 128M) wqkv_bf16    -> reused as attn_bf16 [32M,64M) + wo_bf16 [64M,96M)
//  [128M,160M) Q  [160M,192M) K  [192M,224M) V     (all [b][h][s][d])
extern "C" void kernel_launch(void* const* d_in, const int* in_sizes, int n_in,
                              void* d_out, int out_size, void* d_ws, size_t ws_size,
                              hipStream_t stream) {
  const float* hidden = (const float*)d_in[0];
  const float* cosT = (const float*)d_in[1];
  const float* sinT = (const float*)d_in[2];
  const float* wqkv = (const float*)d_in[3];
  const float* wo = (const float*)d_in[4];
  float* out = (float*)d_out;
  char* ws = (char*)d_ws;

  us* hB = (us*)(ws);
  us* wqB = (us*)(ws + 33554432ull);
  us* Qb = (us*)(ws + 134217728ull);
  us* Kb = (us*)(ws + 167772160ull);
  us* Vb = (us*)(ws + 201326592ull);
  us* VtB = (us*)(ws);                  // reuse hidden_bf16 region
  us* atB = (us*)(ws + 33554432ull);    // reuse wqkv_bf16 region
  us* woB = (us*)(ws + 67108864ull);    // reuse wqkv_bf16 region (2nd third)

  cast2_kernel<<<2048, 256, 0, stream>>>(hidden, hB, 4096 * 4096,
                                         wqkv, wqB, 12288 * 4096);
  gemm8<1><<<768, 512, 0, stream>>>(hB, wqB, 4096, 12288, 4096,
                                    nullptr, Qb, Kb, Vb, cosT, sinT, 16);
  transpose_v<<<dim3(16, 2, 128), 256, 0, stream>>>(Vb, VtB);
  cast_kernel<<<2048, 256, 0, stream>>>(wo, woB, 4096 * 4096);
  attn_kernel<<<dim3(4, 128), 256, 0, stream>>>(Qb, Kb, VtB, atB);
  gemm8<0><<<256, 512, 0, stream>>>(atB, woB, 4096, 4096, 4096,
                                    out, nullptr, nullptr, nullptr, nullptr, nullptr, 16);
}

// Round 16
// 658.275 us; speedup vs baseline: 1.1330x; 1.1330x over previous
//
#include <hip/hip_runtime.h>

typedef unsigned short us;
typedef __bf16 v8bf __attribute__((ext_vector_type(8)));
typedef float v4f __attribute__((ext_vector_type(4)));
typedef us us4v __attribute__((ext_vector_type(4)));
typedef us us8v __attribute__((ext_vector_type(8)));
typedef float f4v __attribute__((ext_vector_type(4)));

#define SCALE 0.08838834764831845f

__device__ __forceinline__ us f2bf(float f) {
  unsigned u = __builtin_bit_cast(unsigned, f);
  u += 0x7fffu + ((u >> 16) & 1u);
  return (us)(u >> 16);
}
__device__ __forceinline__ float bf2f(us h) {
  unsigned u = ((unsigned)h) << 16;
  return __builtin_bit_cast(float, u);
}

typedef const __attribute__((address_space(1))) void* gas_t;
typedef __attribute__((address_space(3))) void* las_t;
#define GLD16(gp, lp) __builtin_amdgcn_global_load_lds((gas_t)(gp), (las_t)(lp), 16, 0, 0)

// ---------------- fp32 -> bf16 casts (wo cast AFTER QKV GEMM: woB aliases
// the middle of wqB — R13/R14 lesson) ----------------
__global__ void cast_kernel(const float* __restrict__ in, us* __restrict__ out, int n) {
  int stride = gridDim.x * blockDim.x * 4;
  for (int i = (blockIdx.x * blockDim.x + threadIdx.x) * 4; i < n; i += stride) {
    f4v f = *(const f4v*)(in + i);
    us4v o;
#pragma unroll
    for (int j = 0; j < 4; ++j) o[j] = f2bf(f[j]);
    *(us4v*)(out + i) = o;
  }
}

__global__ void cast2_kernel(const float* __restrict__ a, us* __restrict__ oa, int na,
                             const float* __restrict__ b, us* __restrict__ ob, int nb) {
  int total = na + nb;
  int stride = gridDim.x * blockDim.x * 4;
  for (int i = (blockIdx.x * blockDim.x + threadIdx.x) * 4; i < total; i += stride) {
    const float* s = (i < na) ? (a + i) : (b + (i - na));
    us* d = (i < na) ? (oa + i) : (ob + (i - na));
    f4v f = *(const f4v*)s;
    us4v o;
#pragma unroll
    for (int j = 0; j < 4; ++j) o[j] = f2bf(f[j]);
    *(us4v*)d = o;
  }
}

// ---------------- 256x256 GEMM, R12 (best measured): 8-phase + lookahead -----
// Stage slots A(t+1)@ph0/ph1, B(t+2)@ph2/ph3+VMC4, A(t+2)@ph4/ph5,
// B(t+3)@ph6/ph7+VMC4; q00 reads post-barrier (race-free: ph3's VMC4 leaves
// only B(t+2)j0-3 => A(t+1)+B(t+1) drained by EVERY wave => ph3-end barrier
// makes buf1 globally valid; symmetric at ph7 for buf0).
// Measured: QKV 362.7us, MfmaUtil 52.8%, 0 bank conflicts, absmax 0.03125.
// (R15's 32x32x16 variant was correct but SLOWER: its fragment read pattern
//  — 32 distinct rows at one fixed 16B chunk — bank-conflicts 3.8e7/dispatch,
//  erasing the 21% matrix-pipe advantage. 16x16x32 retained.)
template <int EPI>
__global__ __launch_bounds__(512, 2) void gemm8(
    const us* __restrict__ A, const us* __restrict__ Bt, int M, int N, int K,
    float* __restrict__ outF, us* __restrict__ outQ, us* __restrict__ outK,
    us* __restrict__ outV, const float* __restrict__ cosT,
    const float* __restrict__ sinT, int MT) {
  __shared__ us lds[65536];  // buf0: A[0,16384) B[16384,32768); buf1: +32768
  const int tid = threadIdx.x, lane = tid & 63, w = tid >> 6;
  const int nwg = gridDim.x;
  const int bid = blockIdx.x;
  const int cpx = nwg >> 3;
  const int swz = (bid & 7) * cpx + (bid >> 3);  // grids %8==0 (768, 256)
  const int bm = swz % MT, bn = swz / MT;
  const int row0 = bm * 256, col0 = bn * 256;
  const int wr = w >> 2, wc = w & 3;
  const int lr = lane & 15, lg = lane >> 4;
  const int NTK = K >> 6;  // even, >=4 (64)

#define STAGE_A(t, p, j)                                                      \
  do {                                                                        \
    int q_ = (j) * 512 + tid;                                                 \
    int row_ = q_ >> 3, cph_ = q_ & 7;                                        \
    GLD16(A + (long)(row0 + row_) * K + (t) * 64 + ((cph_ ^ (row_ & 7)) * 8), \
          &lds[(p) * 32768 + ((j) * 512 + w * 64) * 8]);                      \
  } while (0)
#define STAGE_B(t, p, j)                                                      \
  do {                                                                        \
    int q_ = (j) * 512 + tid;                                                 \
    int row_ = q_ >> 3, cph_ = q_ & 7;                                        \
    GLD16(Bt + (long)(col0 + row_) * K + (t) * 64 + ((cph_ ^ (row_ & 7)) * 8),\
          &lds[(p) * 32768 + 16384 + ((j) * 512 + w * 64) * 8]);              \
  } while (0)

  // wave fragment n -> B-row / C-col remap (RoPE partner d<->d+64 = n^2)
#define COLREL(n) (((wc) >> 1) * 128 + ((n) >> 1) * 64 + ((wc) & 1) * 32 + ((n) & 1) * 16)

// swizzled fragment load (row&7 == lr&7 for all rows we touch)
#define LDF(base, row, kkv) \
  (*(const v8bf*)&(base)[(row) * 64 + (((((kkv) * 4) + lg) ^ ((row) & 7)) * 8)])

#define RD_ALO(base)                                                          \
  af[0][0] = LDF(base, ar0, 0); af[1][0] = LDF(base, ar0 + 16, 0);            \
  af[2][0] = LDF(base, ar0 + 32, 0); af[3][0] = LDF(base, ar0 + 48, 0);       \
  af[0][1] = LDF(base, ar0, 1); af[1][1] = LDF(base, ar0 + 16, 1);            \
  af[2][1] = LDF(base, ar0 + 32, 1); af[3][1] = LDF(base, ar0 + 48, 1);
#define RD_AHI(base)                                                          \
  af[0][0] = LDF(base, ar0 + 64, 0); af[1][0] = LDF(base, ar0 + 80, 0);       \
  af[2][0] = LDF(base, ar0 + 96, 0); af[3][0] = LDF(base, ar0 + 112, 0);      \
  af[0][1] = LDF(base, ar0 + 64, 1); af[1][1] = LDF(base, ar0 + 80, 1);       \
  af[2][1] = LDF(base, ar0 + 96, 1); af[3][1] = LDF(base, ar0 + 112, 1);
#define RD_BLO(base)                                                          \
  bf_lo[0][0] = LDF(base, br0, 0); bf_lo[1][0] = LDF(base, br1, 0);           \
  bf_lo[0][1] = LDF(base, br0, 1); bf_lo[1][1] = LDF(base, br1, 1);
#define RD_BHI(base)                                                          \
  bf_hi[0][0] = LDF(base, br2, 0); bf_hi[1][0] = LDF(base, br3, 0);           \
  bf_hi[0][1] = LDF(base, br2, 1); bf_hi[1][1] = LDF(base, br3, 1);

#define HMFMA(mb, Bf, nb, kkv)                                                \
  _Pragma("unroll") for (int mm = 0; mm < 4; ++mm)                            \
  _Pragma("unroll") for (int nn = 0; nn < 2; ++nn)                            \
    acc[(mb) + mm][(nb) + nn] = __builtin_amdgcn_mfma_f32_16x16x32_bf16(      \
        af[mm][kkv], Bf[nn][kkv], acc[(mb) + mm][(nb) + nn], 0, 0, 0);

#define BARR __builtin_amdgcn_s_barrier()
#define LGKM0 asm volatile("s_waitcnt lgkmcnt(0)" ::: "memory")
#define PRIO1 __builtin_amdgcn_s_setprio(1)
#define PRIO0 __builtin_amdgcn_s_setprio(0)
#define VMC4 asm volatile("s_waitcnt vmcnt(4)" ::: "memory")
#define VMC0 asm volatile("s_waitcnt vmcnt(0)" ::: "memory")

  v4f acc[8][4];
#pragma unroll
  for (int m = 0; m < 8; ++m)
#pragma unroll
    for (int n = 0; n < 4; ++n)
#pragma unroll
      for (int j = 0; j < 4; ++j) acc[m][n][j] = 0.f;

  const us* B0a = &lds[0];
  const us* B0b = &lds[16384];
  const us* B1a = &lds[32768];
  const us* B1b = &lds[49152];
  const int ar0 = wr * 128 + lr;
  const int br0 = COLREL(0) + lr, br1 = COLREL(1) + lr;
  const int br2 = COLREL(2) + lr, br3 = COLREL(3) + lr;

  // prologue: A(0),B(0) -> buf0; B(1) -> buf1. VMC4 drains tile0 for every
  // wave (leaves B(1)'s 4). BARR => buf0 globally valid.
  STAGE_A(0, 0, 0); STAGE_A(0, 0, 1); STAGE_A(0, 0, 2); STAGE_A(0, 0, 3);
  STAGE_B(0, 0, 0); STAGE_B(0, 0, 1); STAGE_B(0, 0, 2); STAGE_B(0, 0, 3);
  STAGE_B(1, 1, 0); STAGE_B(1, 1, 1); STAGE_B(1, 1, 2); STAGE_B(1, 1, 3);
  VMC4;
  BARR;

  v8bf af[4][2], bf_lo[2][2], bf_hi[2][2];

  for (int t = 0; t < NTK; t += 2) {
    // ph0: q00 reads of buf0 (post-barrier, SAFE) | MFMA q00(t) |
    //      read B-hi(buf0) | stage A(t+1) j0,j1
    RD_ALO(B0a); RD_BLO(B0b);
    LGKM0; PRIO1; HMFMA(0, bf_lo, 0, 0); HMFMA(0, bf_lo, 0, 1); PRIO0;
    RD_BHI(B0b);
    STAGE_A(t + 1, 1, 0); STAGE_A(t + 1, 1, 1);
    BARR;
    // ph1: MFMA q01 | read A-hi(buf0) | stage A(t+1) j2,j3
    LGKM0; PRIO1; HMFMA(0, bf_hi, 2, 0); HMFMA(0, bf_hi, 2, 1); PRIO0;
    RD_AHI(B0a);
    STAGE_A(t + 1, 1, 2); STAGE_A(t + 1, 1, 3);
    BARR;
    // ph2: MFMA q10 | stage B(t+2) j0,j1
    LGKM0; PRIO1; HMFMA(4, bf_lo, 0, 0); HMFMA(4, bf_lo, 0, 1); PRIO0;
    if (t + 2 < NTK) { STAGE_B(t + 2, 0, 0); STAGE_B(t + 2, 0, 1); }
    BARR;
    // ph3: MFMA q11 | stage B(t+2) j2,j3 | VMC4: leaves only B(t+2)j0-3 =>
    //      A(t+1)+B(t+1) drained by EVERY wave => ph3-end BARR = buf1 valid
    LGKM0; PRIO1; HMFMA(4, bf_hi, 2, 0); HMFMA(4, bf_hi, 2, 1); PRIO0;
    if (t + 2 < NTK) { STAGE_B(t + 2, 0, 2); STAGE_B(t + 2, 0, 3); VMC4; }
    else { VMC0; }
    BARR;
    // ph4: q00 reads of buf1 (post-barrier, SAFE) | MFMA q00(t+1) |
    //      read B-hi(buf1) | stage A(t+2) j0,j1
    RD_ALO(B1a); RD_BLO(B1b);
    LGKM0; PRIO1; HMFMA(0, bf_lo, 0, 0); HMFMA(0, bf_lo, 0, 1); PRIO0;
    RD_BHI(B1b);
    if (t + 2 < NTK) { STAGE_A(t + 2, 0, 0); STAGE_A(t + 2, 0, 1); }
    BARR;
    // ph5: MFMA q01 | read A-hi(buf1) | stage A(t+2) j2,j3
    LGKM0; PRIO1; HMFMA(0, bf_hi, 2, 0); HMFMA(0, bf_hi, 2, 1); PRIO0;
    RD_AHI(B1a);
    if (t + 2 < NTK) { STAGE_A(t + 2, 0, 2); STAGE_A(t + 2, 0, 3); }
    BARR;
    // ph6: MFMA q10 | stage B(t+3) j0,j1
    LGKM0; PRIO1; HMFMA(4, bf_lo, 0, 0); HMFMA(4, bf_lo, 0, 1); PRIO0;
    if (t + 3 < NTK) { STAGE_B(t + 3, 1, 0); STAGE_B(t + 3, 1, 1); }
    BARR;
    // ph7: MFMA q11 | stage B(t+3) j2,j3 | VMC4: drains A(t+2)+B(t+2) =>
    //      ph7-end BARR = buf0 valid for next ph0's reads
    LGKM0; PRIO1; HMFMA(4, bf_hi, 2, 0); HMFMA(4, bf_hi, 2, 1); PRIO0;
    if (t + 3 < NTK) { STAGE_B(t + 3, 1, 2); STAGE_B(t + 3, 1, 3); VMC4; }
    else if (t + 2 < NTK) { VMC0; }
    BARR;
  }
#undef STAGE_A
#undef STAGE_B

  if (EPI == 0) {
#pragma unroll
    for (int m = 0; m < 8; ++m) {
#pragma unroll
      for (int r = 0; r < 4; ++r) {
        int row = row0 + wr * 128 + m * 16 + lg * 4 + r;
#pragma unroll
        for (int n = 0; n < 4; ++n) {
          int col = col0 + COLREL(n) + lr;
          outF[(long)row * N + col] = acc[m][n][r];
        }
      }
    }
  } else {
    // fused RoPE epilogue, register-local (partner = frag n^2)
    const int cb = col0 + (wc >> 1) * 128;  // head-block base column
    const int which = cb >> 12;             // 0=Q 1=K 2=V
    const int h = (cb >> 7) & 31;
    us* base = (which == 0) ? outQ : ((which == 1) ? outK : outV);
#pragma unroll
    for (int m = 0; m < 8; ++m) {
#pragma unroll
      for (int r = 0; r < 4; ++r) {
        int trow = row0 + wr * 128 + m * 16 + lg * 4 + r;
        int b2 = trow >> 10, spos = trow & 1023;
        us* rowp = base + ((b2 * 32 + h) * 1024 + spos) * 128;
        if (which < 2) {
#pragma unroll
          for (int n = 0; n < 4; ++n) {
            int dl = (wc & 1) * 32 + (n & 1) * 16 + lr;  // d & 63
            float c = cosT[(long)trow * 64 + dl];
            float s = sinT[(long)trow * 64 + dl];
            float own = acc[m][n][r];
            float other = acc[m][n ^ 2][r];
            float y = (n < 2) ? (own * c - other * s) : (own * c + other * s);
            rowp[(n >> 1) * 64 + dl] = f2bf(y);
          }
        } else {
#pragma unroll
          for (int n = 0; n < 4; ++n) {
            int dl = (wc & 1) * 32 + (n & 1) * 16 + lr;
            rowp[(n >> 1) * 64 + dl] = f2bf(acc[m][n][r]);
          }
        }
      }
    }
  }
}

// ---------------- V transpose: [bh][s][d] -> [bh][d][s] ----------------
__global__ void transpose_v(const us* __restrict__ V, us* __restrict__ Vt) {
  __shared__ us tile[64][66];
  const int tid = threadIdx.x;
  const int s0 = blockIdx.x * 64;
  const int d0 = blockIdx.y * 64;
  const int bh = blockIdx.z;
  const us* Vb = V + (long)bh * 131072;
  us* Vtb = Vt + (long)bh * 131072;
  const int rr = tid >> 2, cq = tid & 3;
  us8v v0 = *(const us8v*)(Vb + (s0 + rr) * 128 + d0 + cq * 16);
  us8v v1 = *(const us8v*)(Vb + (s0 + rr) * 128 + d0 + cq * 16 + 8);
#pragma unroll
  for (int j = 0; j < 8; ++j) {
    tile[rr][cq * 16 + j] = v0[j];
    tile[rr][cq * 16 + 8 + j] = v1[j];
  }
  __syncthreads();
  us8v o0, o1;
#pragma unroll
  for (int j = 0; j < 8; ++j) {
    o0[j] = tile[cq * 16 + j][rr];
    o1[j] = tile[cq * 16 + 8 + j][rr];
  }
  *(us8v*)(Vtb + (d0 + rr) * 1024 + s0 + cq * 16) = o0;
  *(us8v*)(Vtb + (d0 + rr) * 1024 + s0 + cq * 16 + 8) = o1;
}

// ---------------- causal flash attention (R6 body + R14 XCD-coloring) --------
// Remap (xcd = L&7, W = L>>3) -> bh = xcd*16 + (W&15), qpair = W>>4
// (bijective; load balance preserved). Each XCD's co-resident blocks share
// 16 bh and the 4 blocks of one bh are co-located -> KV re-reads L2-local.
__global__ __launch_bounds__(256, 2) void attn_kernel(
    const us* __restrict__ Q, const us* __restrict__ Kg,
    const us* __restrict__ Vt, us* __restrict__ Out) {
  __shared__ us Ks[2][8192];
  __shared__ us Vs[2][8192];
  __shared__ us Ps[4 * 2048];
  const int tid = threadIdx.x, lane = tid & 63, w = tid >> 6;
  const int L = (int)blockIdx.y * 4 + (int)blockIdx.x;  // dispatch-linear
  const int xcd = L & 7, W = L >> 3;
  const int bh = xcd * 16 + (W & 15);
  const int qpair = W >> 4;  // [0,4)
  const int lr = lane & 15, lg = lane >> 4;
  const us* Kbase = Kg + (long)bh * 131072;
  const us* Vbase = Vt + (long)bh * 131072;
  us* Pw = &Ps[w * 2048];
  const int b = bh >> 5, h = bh & 31;

#define STAGE_KV(kt, bf)                                                      \
  do {                                                                        \
    _Pragma("unroll") for (int i_ = 0; i_ < 4; ++i_) {                        \
      int c_ = (i_ * 4 + w) * 64 + lane;                                      \
      int rk_ = c_ >> 4, pc_ = c_ & 15;                                       \
      GLD16(Kbase + ((kt) * 64 + rk_) * 128 + ((pc_ ^ (rk_ & 7)) * 8),        \
            &Ks[bf][(i_ * 4 + w) * 512]);                                     \
    }                                                                         \
    _Pragma("unroll") for (int i_ = 0; i_ < 4; ++i_) {                        \
      int c_ = (i_ * 4 + w) * 64 + lane;                                      \
      int dd_ = c_ >> 3, pc_ = c_ & 7;                                        \
      GLD16(Vbase + dd_ * 1024 + (kt) * 64 + ((pc_ ^ (dd_ & 7)) * 8),         \
            &Vs[bf][(i_ * 4 + w) * 512]);                                     \
    }                                                                         \
  } while (0)

#pragma unroll 1
  for (int qsel = 0; qsel < 2; ++qsel) {
    const int qt = qsel ? qpair : 7 - qpair;
    const int q0 = qt * 128 + w * 32;

    v8bf qf[2][4];
    const us* Qb = Q + ((long)bh * 1024 + q0) * 128;
#pragma unroll
    for (int mq = 0; mq < 2; ++mq)
#pragma unroll
      for (int ks = 0; ks < 4; ++ks)
        qf[mq][ks] = *(const v8bf*)(Qb + (mq * 16 + lr) * 128 + ks * 32 + lg * 8);

    float m_run[2][4], l_run[2][4];
    v4f o_acc[2][8];
#pragma unroll
    for (int mq = 0; mq < 2; ++mq) {
#pragma unroll
      for (int r = 0; r < 4; ++r) {
        m_run[mq][r] = -1e30f;
        l_run[mq][r] = 0.f;
      }
#pragma unroll
      for (int nd = 0; nd < 8; ++nd)
#pragma unroll
        for (int j = 0; j < 4; ++j) o_acc[mq][nd][j] = 0.f;
    }

    const int nkt = 2 * qt + 2;
    STAGE_KV(0, 0);
    for (int kt = 0; kt < nkt; ++kt) {
      const int cb = kt & 1;
      if (kt + 1 < nkt) {
        STAGE_KV(kt + 1, cb ^ 1);
        asm volatile("s_waitcnt vmcnt(8)" ::: "memory");
      } else {
        asm volatile("s_waitcnt vmcnt(0)" ::: "memory");
      }
      __builtin_amdgcn_s_barrier();

      v4f sacc[2][4];
#pragma unroll
      for (int mq = 0; mq < 2; ++mq)
#pragma unroll
        for (int nk = 0; nk < 4; ++nk)
#pragma unroll
          for (int j = 0; j < 4; ++j) sacc[mq][nk][j] = 0.f;
      __builtin_amdgcn_s_setprio(1);
#pragma unroll
      for (int nk = 0; nk < 4; ++nk) {
        int key = nk * 16 + lr;
#pragma unroll
        for (int ks = 0; ks < 4; ++ks) {
          int pc = (ks * 4 + lg) ^ (key & 7);
          v8bf kf = *(const v8bf*)(&Ks[cb][key * 128 + pc * 8]);
          sacc[0][nk] = __builtin_amdgcn_mfma_f32_16x16x32_bf16(qf[0][ks], kf, sacc[0][nk], 0, 0, 0);
          sacc[1][nk] = __builtin_amdgcn_mfma_f32_16x16x32_bf16(qf[1][ks], kf, sacc[1][nk], 0, 0, 0);
        }
      }
      __builtin_amdgcn_s_setprio(0);

      const bool needMask = (kt * 64 + 63) > q0;
#pragma unroll
      for (int mq = 0; mq < 2; ++mq)
#pragma unroll
        for (int nk = 0; nk < 4; ++nk)
#pragma unroll
          for (int r = 0; r < 4; ++r) {
            float sv = sacc[mq][nk][r] * SCALE;
            if (needMask && (kt * 64 + nk * 16 + lr) > (q0 + mq * 16 + lg * 4 + r)) sv = -1e30f;
            sacc[mq][nk][r] = sv;
          }

      float pm[2][4];
      float need = 0.f;
#pragma unroll
      for (int mq = 0; mq < 2; ++mq)
#pragma unroll
        for (int r = 0; r < 4; ++r) {
          float p = fmaxf(fmaxf(sacc[mq][0][r], sacc[mq][1][r]),
                          fmaxf(sacc[mq][2][r], sacc[mq][3][r]));
          p = fmaxf(p, __shfl_xor(p, 1));
          p = fmaxf(p, __shfl_xor(p, 2));
          p = fmaxf(p, __shfl_xor(p, 4));
          p = fmaxf(p, __shfl_xor(p, 8));
          pm[mq][r] = p;
          need = fmaxf(need, p - m_run[mq][r]);
        }
      if (__any(need > 8.f)) {
#pragma unroll
        for (int mq = 0; mq < 2; ++mq)
#pragma unroll
          for (int r = 0; r < 4; ++r) {
            float mnew = fmaxf(m_run[mq][r], pm[mq][r]);
            float alpha = __expf(m_run[mq][r] - mnew);
            m_run[mq][r] = mnew;
            l_run[mq][r] *= alpha;
#pragma unroll
            for (int nd = 0; nd < 8; ++nd)
#pragma unroll
              for (int j = 0; j < 4; ++j) o_acc[mq][nd][j] = (j == r) ? o_acc[mq][nd][j] * alpha : o_acc[mq][nd][j];
          }
      }

      float rsum[2][4];
#pragma unroll
      for (int mq = 0; mq < 2; ++mq)
#pragma unroll
        for (int r = 0; r < 4; ++r) rsum[mq][r] = 0.f;
#pragma unroll
      for (int mq = 0; mq < 2; ++mq)
#pragma unroll
        for (int nk = 0; nk < 4; ++nk) {
          int key = nk * 16 + lr;
#pragma unroll
          for (int r = 0; r < 4; ++r) {
            float p = __expf(sacc[mq][nk][r] - m_run[mq][r]);
            rsum[mq][r] += p;
            int qrow = mq * 16 + lg * 4 + r;
            int pcw = (key >> 3) ^ (qrow & 7);
            Pw[qrow * 64 + pcw * 8 + (key & 7)] = f2bf(p);
          }
        }

#pragma unroll
      for (int mq = 0; mq < 2; ++mq)
#pragma unroll
        for (int r = 0; r < 4; ++r) {
          float rs = rsum[mq][r];
          rs += __shfl_xor(rs, 1);
          rs += __shfl_xor(rs, 2);
          rs += __shfl_xor(rs, 4);
          rs += __shfl_xor(rs, 8);
          l_run[mq][r] += rs;
        }

      __builtin_amdgcn_s_setprio(1);
#pragma unroll
      for (int kk = 0; kk < 2; ++kk) {
        v8bf pa[2];
#pragma unroll
        for (int mq = 0; mq < 2; ++mq) {
          int q = mq * 16 + lr;
          int pc = (kk * 4 + lg) ^ (q & 7);
          pa[mq] = *(const v8bf*)(&Pw[q * 64 + pc * 8]);
        }
#pragma unroll
        for (int nd = 0; nd < 8; ++nd) {
          int d = nd * 16 + lr;
          int pc = (kk * 4 + lg) ^ (d & 7);
          v8bf vb = *(const v8bf*)(&Vs[cb][d * 64 + pc * 8]);
          o_acc[0][nd] = __builtin_amdgcn_mfma_f32_16x16x32_bf16(pa[0], vb, o_acc[0][nd], 0, 0, 0);
          o_acc[1][nd] = __builtin_amdgcn_mfma_f32_16x16x32_bf16(pa[1], vb, o_acc[1][nd], 0, 0, 0);
        }
      }
      __builtin_amdgcn_s_setprio(0);
      __builtin_amdgcn_s_barrier();
    }

#pragma unroll
    for (int mq = 0; mq < 2; ++mq)
#pragma unroll
      for (int r = 0; r < 4; ++r) {
        int srow = q0 + mq * 16 + lg * 4 + r;
        float inv = 1.f / l_run[mq][r];
        us* orow = Out + ((long)b * 1024 + srow) * 4096 + h * 128;
#pragma unroll
        for (int nd = 0; nd < 8; ++nd) orow[nd * 16 + lr] = f2bf(o_acc[mq][nd][r] * inv);
      }
  }
#undef STAGE_KV
}

// ---------------- launcher ----------------
// ws layout (bytes), peak 224 MB with reuse. LIFETIME NOTE: woB (64M..96M)
// aliases the middle of wqB (32M..128M) — the wo cast MUST run after the QKV
// GEMM.
//  [0,   32M)  hidden_bf16  -> reused as Vt after QKV GEMM
//  [32M, 128M) wqkv_bf16    -> reused as attn_bf16 [32M,64M) + wo_bf16 [64M,96M)
//  [128M,160M) Q  [160M,192M) K  [192M,224M) V     (all [b][h][s][d])
extern "C" void kernel_launch(void* const* d_in, const int* in_sizes, int n_in,
                              void* d_out, int out_size, void* d_ws, size_t ws_size,
                              hipStream_t stream) {
  const float* hidden = (const float*)d_in[0];
  const float* cosT = (const float*)d_in[1];
  const float* sinT = (const float*)d_in[2];
  const float* wqkv = (const float*)d_in[3];
  const float* wo = (const float*)d_in[4];
  float* out = (float*)d_out;
  char* ws = (char*)d_ws;

  us* hB = (us*)(ws);
  us* wqB = (us*)(ws + 33554432ull);
  us* Qb = (us*)(ws + 134217728ull);
  us* Kb = (us*)(ws + 167772160ull);
  us* Vb = (us*)(ws + 201326592ull);
  us* VtB = (us*)(ws);                  // reuse hidden_bf16 region
  us* atB = (us*)(ws + 33554432ull);    // reuse wqkv_bf16 region
  us* woB = (us*)(ws + 67108864ull);    // reuse wqkv_bf16 region (2nd third)

  cast2_kernel<<<2048, 256, 0, stream>>>(hidden, hB, 4096 * 4096,
                                         wqkv, wqB, 12288 * 4096);
  gemm8<1><<<768, 512, 0, stream>>>(hB, wqB, 4096, 12288, 4096,
                                    nullptr, Qb, Kb, Vb, cosT, sinT, 16);
  transpose_v<<<dim3(16, 2, 128), 256, 0, stream>>>(Vb, VtB);
  cast_kernel<<<2048, 256, 0, stream>>>(wo, woB, 4096 * 4096);
  attn_kernel<<<dim3(4, 128), 256, 0, stream>>>(Qb, Kb, VtB, atB);
  gemm8<0><<<256, 512, 0, stream>>>(atB, woB, 4096, 4096, 4096,
                                    out, nullptr, nullptr, nullptr, nullptr, nullptr, 16);
}